// Round 1
// baseline (848.552 us; speedup 1.0000x reference)
//
#include <hip/hip_runtime.h>
#include <hip/hip_bf16.h>

typedef __hip_bfloat16 bf16;
typedef __attribute__((ext_vector_type(8))) short short8;
typedef __attribute__((ext_vector_type(4))) short short4v;
typedef __attribute__((ext_vector_type(4))) float floatx4;

#define NPIX 65536   // 256*256

__device__ __forceinline__ float b2f(bf16 v) { return __bfloat162float(v); }
__device__ __forceinline__ bf16 f2b(float v) { return __float2bfloat16(v); }
__device__ __forceinline__ short f2bs(float v) { bf16 t = __float2bfloat16(v); return *(short*)&t; }
__device__ __forceinline__ float us2f(unsigned short u) {
  union { unsigned int i; float f; } t; t.i = ((unsigned int)u) << 16; return t.f;
}
__device__ __forceinline__ float gelu_f(float v) {
  return 0.5f * v * (1.f + erff(v * 0.7071067811865476f));
}

// ---- workspace layout (bytes) ----
#define OFF_QKV 0u            // bf16 [192, NPIX]: q planes 0..63, k 64..127;
                              //   region 128..191 holds o as PIXEL-MAJOR [NPIX][64]
#define OFF_KV  25165824u     // fp32 [2,8,72,8]
#define OFF_KS  25202688u     // fp32 [2,8,72]
#define OFF_WP  25207296u     // bf16 wpack[9][64co][64ci] = 73,728 B

__global__ void k_zero(float* __restrict__ p, int n) {
  int i = blockIdx.x * 256 + threadIdx.x;
  if (i < n) p[i] = 0.f;
}

// pack proj_w [co][ci][p] fp32 -> wpack[p][co][ci] bf16 (A-fragment b128 source)
__global__ void k_pack(const float* __restrict__ pw, bf16* __restrict__ wpack) {
  int i = blockIdx.x * 256 + threadIdx.x;   // [0, 36864)
  int p = i >> 12, rem = i & 4095;
  int co = rem >> 6, ci = rem & 63;
  wpack[i] = f2b(pw[(co * 64 + ci) * 9 + p]);
}

// ============ shared MFMA-GEMM staging ============
__device__ __forceinline__ void stage_f32(const float* __restrict__ src, bf16* tile) {
  int tid = threadIdx.x;
  int px = tid & 127, chalf = tid >> 7;
#pragma unroll
  for (int it = 0; it < 8; ++it) {
    int ci0 = it * 8 + chalf * 4;
    short4v w;
#pragma unroll
    for (int j = 0; j < 4; ++j) w[j] = f2bs(src[((size_t)(ci0 + j) << 16) + px]);
    *(short4v*)&tile[px * 72 + ci0] = w;
  }
}

__device__ __forceinline__ void stage_bf16(const bf16* __restrict__ src, bf16* tile) {
  int tid = threadIdx.x;
  int px = tid & 127, chalf = tid >> 7;
  const unsigned short* s = (const unsigned short*)src;
#pragma unroll
  for (int it = 0; it < 8; ++it) {
    int ci0 = it * 8 + chalf * 4;
    short4v w;
#pragma unroll
    for (int j = 0; j < 4; ++j) w[j] = (short)s[((size_t)(ci0 + j) << 16) + px];
    *(short4v*)&tile[px * 72 + ci0] = w;
  }
}

// ============ qkv 1x1 conv via MFMA: grid (512 n-tiles, 3 sec) ============
__global__ __launch_bounds__(256) void k_qkv_mfma(const float* __restrict__ x,
                                                  const float* __restrict__ qkv_w,
                                                  const float* __restrict__ qkv_b,
                                                  bf16* __restrict__ qkv, int b) {
  __shared__ __align__(16) bf16 tile[128 * 72];
  int tid = threadIdx.x;
  int wv = tid >> 6, ln = tid & 63;
  int n0 = blockIdx.x << 7, sec = blockIdx.y;
  stage_f32(x + ((size_t)b << 22) + n0, tile);

  int m = ln & 15, quad = ln >> 4;
  int co = wv * 16 + m;
  const float* w = qkv_w + sec * 4096;
  short8 afrag[2];
#pragma unroll
  for (int s = 0; s < 2; ++s) {
    short8 af;
#pragma unroll
    for (int j = 0; j < 8; ++j) af[j] = f2bs(w[co * 64 + s * 32 + quad * 8 + j]);
    afrag[s] = af;
  }
  __syncthreads();

  floatx4 acc[8];
#pragma unroll
  for (int nt = 0; nt < 8; ++nt) acc[nt] = (floatx4){0.f, 0.f, 0.f, 0.f};
#pragma unroll
  for (int s = 0; s < 2; ++s) {
    int base = m * 72 + s * 32 + quad * 8;
#pragma unroll
    for (int nt = 0; nt < 8; ++nt) {
      short8 bfrag = *(const short8*)&tile[base + nt * 16 * 72];
      acc[nt] = __builtin_amdgcn_mfma_f32_16x16x32_bf16(afrag[s], bfrag, acc[nt], 0, 0, 0);
    }
  }

  bool relu = (sec < 2);
#pragma unroll
  for (int r = 0; r < 4; ++r) {
    int co_r = wv * 16 + quad * 4 + r;
    float bias = qkv_b[sec * 64 + co_r];
    bf16* op = qkv + ((size_t)(sec * 64 + co_r) << 16) + n0;
#pragma unroll
    for (int nt = 0; nt < 8; ++nt) {
      float v = acc[nt][r] + bias;
      if (relu) v = fmaxf(v, 0.f);
      op[nt * 16 + m] = f2b(v);
    }
  }
}

// ============ ffn1 1x1 conv + GELU via MFMA: grid 512 ============
__global__ __launch_bounds__(256) void k_ffn1_mfma(const float* __restrict__ xin,
                                                   const float* __restrict__ w1,
                                                   const float* __restrict__ b1,
                                                   bf16* __restrict__ qkv, int b) {
  __shared__ __align__(16) bf16 tile[128 * 72];
  int tid = threadIdx.x;
  int wv = tid >> 6, ln = tid & 63;
  int n0 = blockIdx.x << 7;
  stage_f32(xin + ((size_t)b << 22) + n0, tile);

  int m = ln & 15, quad = ln >> 4;
  int co = wv * 16 + m;
  short8 afrag[2];
#pragma unroll
  for (int s = 0; s < 2; ++s) {
    short8 af;
#pragma unroll
    for (int j = 0; j < 8; ++j) af[j] = f2bs(w1[co * 64 + s * 32 + quad * 8 + j]);
    afrag[s] = af;
  }
  __syncthreads();

  floatx4 acc[8];
#pragma unroll
  for (int nt = 0; nt < 8; ++nt) acc[nt] = (floatx4){0.f, 0.f, 0.f, 0.f};
#pragma unroll
  for (int s = 0; s < 2; ++s) {
    int base = m * 72 + s * 32 + quad * 8;
#pragma unroll
    for (int nt = 0; nt < 8; ++nt) {
      short8 bfrag = *(const short8*)&tile[base + nt * 16 * 72];
      acc[nt] = __builtin_amdgcn_mfma_f32_16x16x32_bf16(afrag[s], bfrag, acc[nt], 0, 0, 0);
    }
  }

#pragma unroll
  for (int r = 0; r < 4; ++r) {
    int co_r = wv * 16 + quad * 4 + r;
    float bias = b1[co_r];
    bf16* op = qkv + ((size_t)co_r << 16) + n0;
#pragma unroll
    for (int nt = 0; nt < 8; ++nt)
      op[nt * 16 + m] = f2b(gelu_f(acc[nt][r] + bias));
  }
}

// ============ ffn2 1x1 conv + residual via MFMA: grid 512 ============
__global__ __launch_bounds__(256) void k_ffn2_mfma(const bf16* __restrict__ qkv,
                                                   const float* __restrict__ w2,
                                                   const float* __restrict__ b2,
                                                   float* __restrict__ out, int b) {
  __shared__ __align__(16) bf16 tile[128 * 72];
  int tid = threadIdx.x;
  int wv = tid >> 6, ln = tid & 63;
  int n0 = blockIdx.x << 7;
  stage_bf16(qkv + ((size_t)64 << 16) + n0, tile);   // h2 in k planes

  int m = ln & 15, quad = ln >> 4;
  int co = wv * 16 + m;
  short8 afrag[2];
#pragma unroll
  for (int s = 0; s < 2; ++s) {
    short8 af;
#pragma unroll
    for (int j = 0; j < 8; ++j) af[j] = f2bs(w2[co * 64 + s * 32 + quad * 8 + j]);
    afrag[s] = af;
  }
  __syncthreads();

  floatx4 acc[8];
#pragma unroll
  for (int nt = 0; nt < 8; ++nt) acc[nt] = (floatx4){0.f, 0.f, 0.f, 0.f};
#pragma unroll
  for (int s = 0; s < 2; ++s) {
    int base = m * 72 + s * 32 + quad * 8;
#pragma unroll
    for (int nt = 0; nt < 8; ++nt) {
      short8 bfrag = *(const short8*)&tile[base + nt * 16 * 72];
      acc[nt] = __builtin_amdgcn_mfma_f32_16x16x32_bf16(afrag[s], bfrag, acc[nt], 0, 0, 0);
    }
  }

#pragma unroll
  for (int r = 0; r < 4; ++r) {
    int co_r = wv * 16 + quad * 4 + r;
    float bias = b2[co_r];
    float* op = out + ((size_t)b << 22) + ((size_t)co_r << 16) + n0;
#pragma unroll
    for (int nt = 0; nt < 8; ++nt) {
      int i = nt * 16 + m;
      op[i] = op[i] + bias + acc[nt][r];
    }
  }
}

__device__ __forceinline__ void loadrow3(const unsigned short* __restrict__ kp,
                                         int y, int x, float w[3]) {
  if ((unsigned)y < 256u) {
    const unsigned short* r = kp + y * 256;
    w[0] = (x > 0) ? us2f(r[x - 1]) : 0.f;
    w[1] = us2f(r[x]);
    w[2] = (x < 255) ? us2f(r[x + 1]) : 0.f;
  } else {
    w[0] = w[1] = w[2] = 0.f;
  }
}

__device__ __forceinline__ void loadv8(const unsigned short* __restrict__ vp,
                                       int y, int x, float vf[8]) {
#pragma unroll
  for (int e = 0; e < 8; ++e) vf[e] = us2f(vp[((size_t)e << 16) + y * 256 + x]);
}

// DPP butterfly add: v += dpp_permute(v). VALU-only, no DS-pipe traffic.
template <int CTRL>
__device__ __forceinline__ float dpp_add(float v) {
  int t = __builtin_amdgcn_update_dpp(0, __builtin_bit_cast(int, v), CTRL, 0xf, 0xf, true);
  return v + __builtin_bit_cast(float, t);
}

// sum across each row of 16 lanes (result in all 16 lanes of the row)
__device__ __forceinline__ float rowsum16(float v) {
  v = dpp_add<0xB1>(v);   // quad_perm(1,0,3,2)  : xor 1
  v = dpp_add<0x4E>(v);   // quad_perm(2,3,0,1)  : xor 2
  v = dpp_add<0x141>(v);  // row_half_mirror     : xor 4 (groups of 4 equal)
  v = dpp_add<0x140>(v);  // row_mirror          : xor 8 (groups of 8 equal)
  return v;
}

// Attention stats v5: 8-row chunks (grid 2048 blocks) + DPP reduction.
// v4 was latency-bound: 1024 blocks (16 waves/CU max) + 567 DS-ops/wave butterfly.
__global__ __launch_bounds__(256, 6) void k_stats(const bf16* __restrict__ qkv,
                                                  float* __restrict__ kv,
                                                  float* __restrict__ ksum, int b) {
  int tid = threadIdx.x;
  int chunk = blockIdx.x, c = blockIdx.y, h = blockIdx.z;
  const unsigned short* kp = (const unsigned short*)qkv + (((size_t)(64 + h * 8 + c)) << 16);
  const unsigned short* vp = (const unsigned short*)qkv + (((size_t)(128 + h * 8)) << 16);
  int x = tid;
  int y0 = chunk << 3;   // 8 rows per block

  float acc[9][8], ks[9];
#pragma unroll
  for (int p = 0; p < 9; ++p) {
    ks[p] = 0.f;
#pragma unroll
    for (int e = 0; e < 8; ++e) acc[p][e] = 0.f;
  }

  float wm1[3], w0[3], wp1[3], vf[8], knext[3], vnext[8];
  loadrow3(kp, y0 - 1, x, wm1);
  loadrow3(kp, y0, x, w0);
  loadrow3(kp, y0 + 1, x, wp1);
  loadv8(vp, y0, x, vf);
  loadrow3(kp, y0 + 2, x, knext);
  loadv8(vp, (y0 + 1 < 256) ? y0 + 1 : 255, x, vnext);

  for (int i = 0; i < 8; ++i) {
    int y = y0 + i;
#pragma unroll
    for (int t = 0; t < 3; ++t) {
      ks[t] += wm1[t];
      ks[3 + t] += w0[t];
      ks[6 + t] += wp1[t];
#pragma unroll
      for (int e = 0; e < 8; ++e) {
        acc[t][e] = fmaf(wm1[t], vf[e], acc[t][e]);
        acc[3 + t][e] = fmaf(w0[t], vf[e], acc[3 + t][e]);
        acc[6 + t][e] = fmaf(wp1[t], vf[e], acc[6 + t][e]);
      }
    }
#pragma unroll
    for (int t = 0; t < 3; ++t) { wm1[t] = w0[t]; w0[t] = wp1[t]; wp1[t] = knext[t]; }
#pragma unroll
    for (int e = 0; e < 8; ++e) vf[e] = vnext[e];
    loadrow3(kp, y + 3, x, knext);
    int yv = y + 2;
    loadv8(vp, (yv < 256) ? yv : 255, x, vnext);
  }

  // Reduction: DPP sums within each 16-lane row (VALU), then transpose the
  // 16 row-partials per value through LDS and finish with 81 threads.
  __shared__ float red[16][81];
  int r16 = tid >> 4;
  bool wr = (tid & 15) == 0;
#pragma unroll
  for (int p = 0; p < 9; ++p) {
#pragma unroll
    for (int e = 0; e < 8; ++e) {
      float s = rowsum16(acc[p][e]);
      if (wr) red[r16][p * 8 + e] = s;
    }
    float s = rowsum16(ks[p]);
    if (wr) red[r16][72 + p] = s;
  }
  __syncthreads();
  if (tid < 81) {
    float s = 0.f;
#pragma unroll
    for (int j = 0; j < 16; ++j) s += red[j][tid];
    int dbase = (b * 8 + h) * 72 + c * 9;
    if (tid < 72) atomicAdd(&kv[((dbase + (tid >> 3)) << 3) + (tid & 7)], s);
    else atomicAdd(&ksum[dbase + (tid - 72)], s);
  }
}

// o -> PIXEL-MAJOR opx[n][64]: one 16B store per thread (channels h*8..h*8+7).
__global__ __launch_bounds__(256) void k_apply(bf16* __restrict__ qkv,
                                               bf16* __restrict__ opx,
                                               const float* __restrict__ kv,
                                               const float* __restrict__ ksum, int b) {
  int blk = blockIdx.x;
  int chunk = blk & 255, h = blk >> 8;
  int n = (chunk << 8) + threadIdx.x;
  int y = n >> 8, xx = n & 255;
  const float* kvb = kv + (size_t)((b * 8 + h) * 72) * 8;
  const float* ksb = ksum + (b * 8 + h) * 72;
  float num[8] = {0.f, 0.f, 0.f, 0.f, 0.f, 0.f, 0.f, 0.f};
  float den = 0.f;
  for (int c = 0; c < 8; ++c) {
    const bf16* qp = qkv + ((size_t)(h * 8 + c) << 16);
#pragma unroll
    for (int p = 0; p < 9; ++p) {
      int yy = y + p / 3 - 1, xc = xx + p % 3 - 1;
      float qv = 0.f;
      if ((unsigned)yy < 256u && (unsigned)xc < 256u) qv = b2f(qp[yy * 256 + xc]);
      int d = c * 9 + p;
      den = fmaf(qv, ksb[d], den);
#pragma unroll
      for (int e = 0; e < 8; ++e) num[e] = fmaf(qv, kvb[d * 8 + e], num[e]);
    }
  }
  float inv = 1.f / (den + 1e-6f);
  short8 ov;
#pragma unroll
  for (int e = 0; e < 8; ++e) ov[e] = f2bs(num[e] * inv);
  *(short8*)&opx[((size_t)n << 6) + h * 8] = ov;
}

// proj 3x3 conv via MFMA, LDS-free: B-fragments loaded directly from pixel-major opx.
// Grid dim3(2, 256); 256 thr; wave wv -> co [16wv,16wv+16).
__global__ __launch_bounds__(256) void k_proj_mfma(const bf16* __restrict__ opx,
                                                   const bf16* __restrict__ wpack,
                                                   const float* __restrict__ proj_b,
                                                   const float* __restrict__ x,
                                                   float* __restrict__ out, int b) {
  int tid = threadIdx.x;
  int wv = tid >> 6, ln = tid & 63;
  int half = blockIdx.x, y = blockIdx.y;
  int x0 = half << 7;
  int m = ln & 15, quad = ln >> 4;
  int co = wv * 16 + m;

  short8 afrag[18];
#pragma unroll
  for (int s = 0; s < 18; ++s) {
    int p = s >> 1;
    int ci0 = (s & 1) * 32 + quad * 8;
    afrag[s] = *(const short8*)&wpack[(p * 64 + co) * 64 + ci0];
  }

  floatx4 acc[8];
#pragma unroll
  for (int nt = 0; nt < 8; ++nt) acc[nt] = (floatx4){0.f, 0.f, 0.f, 0.f};

#pragma unroll
  for (int s = 0; s < 18; ++s) {
    int p = s >> 1;
    int dy = p / 3 - 1, dx = p % 3 - 1;
    int ci0 = (s & 1) * 32 + quad * 8;
    int gy = y + dy;
    bool yok = (unsigned)gy < 256u;
#pragma unroll
    for (int nt = 0; nt < 8; ++nt) {
      int gx = x0 + nt * 16 + m + dx;
      bool ok = yok && (unsigned)gx < 256u;
      int px = ok ? ((gy << 8) + gx) : 0;
      short8 bfrag = *(const short8*)&opx[((size_t)px << 6) + ci0];
      if (!ok) {
        short8 z = {0, 0, 0, 0, 0, 0, 0, 0};
        bfrag = z;
      }
      acc[nt] = __builtin_amdgcn_mfma_f32_16x16x32_bf16(afrag[s], bfrag, acc[nt], 0, 0, 0);
    }
  }

  float bias4[4];
#pragma unroll
  for (int r = 0; r < 4; ++r) bias4[r] = proj_b[wv * 16 + quad * 4 + r];
#pragma unroll
  for (int nt = 0; nt < 8; ++nt) {
    int gx = x0 + nt * 16 + m;
#pragma unroll
    for (int r = 0; r < 4; ++r) {
      int co_r = wv * 16 + quad * 4 + r;
      size_t idx = ((size_t)(b * 64 + co_r) << 16) + (y << 8) + gx;
      out[idx] = x[idx] + bias4[r] + acc[nt][r];
    }
  }
}

// depthwise 3x3 + GELU: h1 (q planes) -> h2 (k planes). Thread = element.
__global__ __launch_bounds__(256) void k_dw(bf16* __restrict__ qkv,
                                            const float* __restrict__ dw_w,
                                            const float* __restrict__ dw_b) {
  int gid = blockIdx.x * 256 + threadIdx.x;   // [0, 64*NPIX)
  int n = gid & 65535;
  int c = gid >> 16;
  int y = n >> 8, xx = n & 255;
  const bf16* ip = qkv + ((size_t)c << 16);
  float acc = dw_b[c];
#pragma unroll
  for (int p = 0; p < 9; ++p) {
    int yy = y + p / 3 - 1, xc = xx + p % 3 - 1;
    if ((unsigned)yy < 256u && (unsigned)xc < 256u)
      acc = fmaf(b2f(ip[yy * 256 + xc]), dw_w[c * 9 + p], acc);
  }
  qkv[((size_t)(64 + c) << 16) + n] = f2b(gelu_f(acc));
}

extern "C" void kernel_launch(void* const* d_in, const int* in_sizes, int n_in,
                              void* d_out, int out_size, void* d_ws, size_t ws_size,
                              hipStream_t stream) {
  const float* x      = (const float*)d_in[0];
  const float* qkv_w  = (const float*)d_in[1];
  const float* qkv_b  = (const float*)d_in[2];
  const float* proj_w = (const float*)d_in[3];
  const float* proj_b = (const float*)d_in[4];
  const float* ffn1_w = (const float*)d_in[5];
  const float* ffn1_b = (const float*)d_in[6];
  const float* dw_w   = (const float*)d_in[7];
  const float* dw_b   = (const float*)d_in[8];
  const float* ffn2_w = (const float*)d_in[9];
  const float* ffn2_b = (const float*)d_in[10];
  float* out = (float*)d_out;

  char* ws = (char*)d_ws;
  bf16*  qkvb  = (bf16*)(ws + OFF_QKV);
  bf16*  opx   = qkvb + ((size_t)128 << 16);   // v region, pixel-major [NPIX][64]
  float* kvb   = (float*)(ws + OFF_KV);
  float* ksb   = (float*)(ws + OFF_KS);
  bf16*  wpack = (bf16*)(ws + OFF_WP);

  k_zero<<<41, 256, 0, stream>>>(kvb, 10368);  // kv (9216) + ksum (1152), contiguous
  k_pack<<<144, 256, 0, stream>>>(proj_w, wpack);

  for (int b = 0; b < 2; ++b) {
    k_qkv_mfma<<<dim3(512, 3), 256, 0, stream>>>(x, qkv_w, qkv_b, qkvb, b);
    k_stats<<<dim3(32, 8, 8), 256, 0, stream>>>(qkvb, kvb, ksb, b);
    k_apply<<<2048, 256, 0, stream>>>(qkvb, opx, kvb, ksb, b);
    k_proj_mfma<<<dim3(2, 256), 256, 0, stream>>>(opx, wpack, proj_b, x, out, b);
    k_ffn1_mfma<<<512, 256, 0, stream>>>(out, ffn1_w, ffn1_b, qkvb, b);
    k_dw<<<16384, 256, 0, stream>>>(qkvb, dw_w, dw_b);
    k_ffn2_mfma<<<512, 256, 0, stream>>>(qkvb, ffn2_w, ffn2_b, out, b);
  }
}

// Round 2
// 467.111 us; speedup vs baseline: 1.8166x; 1.8166x over previous
//
#include <hip/hip_runtime.h>
#include <hip/hip_bf16.h>

typedef __hip_bfloat16 bf16;
typedef __attribute__((ext_vector_type(8))) short short8;
typedef __attribute__((ext_vector_type(4))) short short4v;
typedef __attribute__((ext_vector_type(4))) float floatx4;

#define NPIX 65536   // 256*256

__device__ __forceinline__ float b2f(bf16 v) { return __bfloat162float(v); }
__device__ __forceinline__ bf16 f2b(float v) { return __float2bfloat16(v); }
__device__ __forceinline__ short f2bs(float v) { bf16 t = __float2bfloat16(v); return *(short*)&t; }
__device__ __forceinline__ float us2f(unsigned short u) {
  union { unsigned int i; float f; } t; t.i = ((unsigned int)u) << 16; return t.f;
}
__device__ __forceinline__ float gelu_f(float v) {
  return 0.5f * v * (1.f + erff(v * 0.7071067811865476f));
}

// ---- workspace layout (bytes) ----
#define OFF_QKV 0u            // bf16 [192, NPIX]: q planes 0..63, k 64..127;
                              //   region 128..191 holds o as PIXEL-MAJOR [NPIX][64]
#define OFF_KV  25165824u     // fp32 [2,8,72,8]
#define OFF_KS  25202688u     // fp32 [2,8,72]
#define OFF_WP  25207296u     // bf16 wpack[9][64co][64ci] = 73,728 B

__global__ void k_zero(float* __restrict__ p, int n) {
  int i = blockIdx.x * 256 + threadIdx.x;
  if (i < n) p[i] = 0.f;
}

// pack proj_w [co][ci][p] fp32 -> wpack[p][co][ci] bf16 (A-fragment b128 source)
__global__ void k_pack(const float* __restrict__ pw, bf16* __restrict__ wpack) {
  int i = blockIdx.x * 256 + threadIdx.x;   // [0, 36864)
  int p = i >> 12, rem = i & 4095;
  int co = rem >> 6, ci = rem & 63;
  wpack[i] = f2b(pw[(co * 64 + ci) * 9 + p]);
}

// ============ shared MFMA-GEMM staging ============
__device__ __forceinline__ void stage_f32(const float* __restrict__ src, bf16* tile) {
  int tid = threadIdx.x;
  int px = tid & 127, chalf = tid >> 7;
#pragma unroll
  for (int it = 0; it < 8; ++it) {
    int ci0 = it * 8 + chalf * 4;
    short4v w;
#pragma unroll
    for (int j = 0; j < 4; ++j) w[j] = f2bs(src[((size_t)(ci0 + j) << 16) + px]);
    *(short4v*)&tile[px * 72 + ci0] = w;
  }
}

__device__ __forceinline__ void stage_bf16(const bf16* __restrict__ src, bf16* tile) {
  int tid = threadIdx.x;
  int px = tid & 127, chalf = tid >> 7;
  const unsigned short* s = (const unsigned short*)src;
#pragma unroll
  for (int it = 0; it < 8; ++it) {
    int ci0 = it * 8 + chalf * 4;
    short4v w;
#pragma unroll
    for (int j = 0; j < 4; ++j) w[j] = (short)s[((size_t)(ci0 + j) << 16) + px];
    *(short4v*)&tile[px * 72 + ci0] = w;
  }
}

// ============ qkv 1x1 conv via MFMA: grid (512 n-tiles, 3 sec) ============
__global__ __launch_bounds__(256) void k_qkv_mfma(const float* __restrict__ x,
                                                  const float* __restrict__ qkv_w,
                                                  const float* __restrict__ qkv_b,
                                                  bf16* __restrict__ qkv, int b) {
  __shared__ __align__(16) bf16 tile[128 * 72];
  int tid = threadIdx.x;
  int wv = tid >> 6, ln = tid & 63;
  int n0 = blockIdx.x << 7, sec = blockIdx.y;
  stage_f32(x + ((size_t)b << 22) + n0, tile);

  int m = ln & 15, quad = ln >> 4;
  int co = wv * 16 + m;
  const float* w = qkv_w + sec * 4096;
  short8 afrag[2];
#pragma unroll
  for (int s = 0; s < 2; ++s) {
    short8 af;
#pragma unroll
    for (int j = 0; j < 8; ++j) af[j] = f2bs(w[co * 64 + s * 32 + quad * 8 + j]);
    afrag[s] = af;
  }
  __syncthreads();

  floatx4 acc[8];
#pragma unroll
  for (int nt = 0; nt < 8; ++nt) acc[nt] = (floatx4){0.f, 0.f, 0.f, 0.f};
#pragma unroll
  for (int s = 0; s < 2; ++s) {
    int base = m * 72 + s * 32 + quad * 8;
#pragma unroll
    for (int nt = 0; nt < 8; ++nt) {
      short8 bfrag = *(const short8*)&tile[base + nt * 16 * 72];
      acc[nt] = __builtin_amdgcn_mfma_f32_16x16x32_bf16(afrag[s], bfrag, acc[nt], 0, 0, 0);
    }
  }

  bool relu = (sec < 2);
#pragma unroll
  for (int r = 0; r < 4; ++r) {
    int co_r = wv * 16 + quad * 4 + r;
    float bias = qkv_b[sec * 64 + co_r];
    bf16* op = qkv + ((size_t)(sec * 64 + co_r) << 16) + n0;
#pragma unroll
    for (int nt = 0; nt < 8; ++nt) {
      float v = acc[nt][r] + bias;
      if (relu) v = fmaxf(v, 0.f);
      op[nt * 16 + m] = f2b(v);
    }
  }
}

// ============ ffn1 1x1 conv + GELU via MFMA: grid 512 ============
__global__ __launch_bounds__(256) void k_ffn1_mfma(const float* __restrict__ xin,
                                                   const float* __restrict__ w1,
                                                   const float* __restrict__ b1,
                                                   bf16* __restrict__ qkv, int b) {
  __shared__ __align__(16) bf16 tile[128 * 72];
  int tid = threadIdx.x;
  int wv = tid >> 6, ln = tid & 63;
  int n0 = blockIdx.x << 7;
  stage_f32(xin + ((size_t)b << 22) + n0, tile);

  int m = ln & 15, quad = ln >> 4;
  int co = wv * 16 + m;
  short8 afrag[2];
#pragma unroll
  for (int s = 0; s < 2; ++s) {
    short8 af;
#pragma unroll
    for (int j = 0; j < 8; ++j) af[j] = f2bs(w1[co * 64 + s * 32 + quad * 8 + j]);
    afrag[s] = af;
  }
  __syncthreads();

  floatx4 acc[8];
#pragma unroll
  for (int nt = 0; nt < 8; ++nt) acc[nt] = (floatx4){0.f, 0.f, 0.f, 0.f};
#pragma unroll
  for (int s = 0; s < 2; ++s) {
    int base = m * 72 + s * 32 + quad * 8;
#pragma unroll
    for (int nt = 0; nt < 8; ++nt) {
      short8 bfrag = *(const short8*)&tile[base + nt * 16 * 72];
      acc[nt] = __builtin_amdgcn_mfma_f32_16x16x32_bf16(afrag[s], bfrag, acc[nt], 0, 0, 0);
    }
  }

#pragma unroll
  for (int r = 0; r < 4; ++r) {
    int co_r = wv * 16 + quad * 4 + r;
    float bias = b1[co_r];
    bf16* op = qkv + ((size_t)co_r << 16) + n0;
#pragma unroll
    for (int nt = 0; nt < 8; ++nt)
      op[nt * 16 + m] = f2b(gelu_f(acc[nt][r] + bias));
  }
}

// ============ ffn2 1x1 conv + residual via MFMA: grid 512 ============
__global__ __launch_bounds__(256) void k_ffn2_mfma(const bf16* __restrict__ qkv,
                                                   const float* __restrict__ w2,
                                                   const float* __restrict__ b2,
                                                   float* __restrict__ out, int b) {
  __shared__ __align__(16) bf16 tile[128 * 72];
  int tid = threadIdx.x;
  int wv = tid >> 6, ln = tid & 63;
  int n0 = blockIdx.x << 7;
  stage_bf16(qkv + ((size_t)64 << 16) + n0, tile);   // h2 in k planes

  int m = ln & 15, quad = ln >> 4;
  int co = wv * 16 + m;
  short8 afrag[2];
#pragma unroll
  for (int s = 0; s < 2; ++s) {
    short8 af;
#pragma unroll
    for (int j = 0; j < 8; ++j) af[j] = f2bs(w2[co * 64 + s * 32 + quad * 8 + j]);
    afrag[s] = af;
  }
  __syncthreads();

  floatx4 acc[8];
#pragma unroll
  for (int nt = 0; nt < 8; ++nt) acc[nt] = (floatx4){0.f, 0.f, 0.f, 0.f};
#pragma unroll
  for (int s = 0; s < 2; ++s) {
    int base = m * 72 + s * 32 + quad * 8;
#pragma unroll
    for (int nt = 0; nt < 8; ++nt) {
      short8 bfrag = *(const short8*)&tile[base + nt * 16 * 72];
      acc[nt] = __builtin_amdgcn_mfma_f32_16x16x32_bf16(afrag[s], bfrag, acc[nt], 0, 0, 0);
    }
  }

#pragma unroll
  for (int r = 0; r < 4; ++r) {
    int co_r = wv * 16 + quad * 4 + r;
    float bias = b2[co_r];
    float* op = out + ((size_t)b << 22) + ((size_t)co_r << 16) + n0;
#pragma unroll
    for (int nt = 0; nt < 8; ++nt) {
      int i = nt * 16 + m;
      op[i] = op[i] + bias + acc[nt][r];
    }
  }
}

__device__ __forceinline__ void loadrow3(const unsigned short* __restrict__ kp,
                                         int y, int x, float w[3]) {
  if ((unsigned)y < 256u) {
    const unsigned short* r = kp + y * 256;
    w[0] = (x > 0) ? us2f(r[x - 1]) : 0.f;
    w[1] = us2f(r[x]);
    w[2] = (x < 255) ? us2f(r[x + 1]) : 0.f;
  } else {
    w[0] = w[1] = w[2] = 0.f;
  }
}

__device__ __forceinline__ void loadv8(const unsigned short* __restrict__ vp,
                                       int y, int x, float vf[8]) {
#pragma unroll
  for (int e = 0; e < 8; ++e) vf[e] = us2f(vp[((size_t)e << 16) + y * 256 + x]);
}

// DPP butterfly add: v += dpp_permute(v). VALU-only, no DS-pipe traffic.
template <int CTRL>
__device__ __forceinline__ float dpp_add(float v) {
  int t = __builtin_amdgcn_update_dpp(0, __builtin_bit_cast(int, v), CTRL, 0xf, 0xf, true);
  return v + __builtin_bit_cast(float, t);
}

// sum across each row of 16 lanes (result in all 16 lanes of the row)
__device__ __forceinline__ float rowsum16(float v) {
  v = dpp_add<0xB1>(v);   // quad_perm(1,0,3,2)  : xor 1
  v = dpp_add<0x4E>(v);   // quad_perm(2,3,0,1)  : xor 2
  v = dpp_add<0x141>(v);  // row_half_mirror     : xor 4
  v = dpp_add<0x140>(v);  // row_mirror          : xor 8
  return v;
}

// Attention stats v6: dy-split. Each block handles ONE row-offset (3 taps),
// so accumulator state is acc[3][8]+ks[3] = 27 floats -> target <=64 VGPR
// for 8 waves/SIMD. Grid 6144 blocks (24/CU demand).
// v5 lesson: __launch_bounds__(256,6) hard-capped VGPR=40 -> accumulator
// spill -> 754 MB scratch writes/dispatch. NEVER cap; shrink state instead.
__global__ __launch_bounds__(256) void k_stats(const bf16* __restrict__ qkv,
                                               float* __restrict__ kv,
                                               float* __restrict__ ksum, int b) {
  int tid = threadIdx.x;
  int bx = blockIdx.x;                 // [0,96): chunk*3 + dy
  int chunk = bx / 3;
  int dy = bx - chunk * 3;             // row offset index: k row = y + dy - 1
  int c = blockIdx.y, h = blockIdx.z;
  const unsigned short* kp = (const unsigned short*)qkv + (((size_t)(64 + h * 8 + c)) << 16);
  const unsigned short* vp = (const unsigned short*)qkv + (((size_t)(128 + h * 8)) << 16);
  int x = tid;
  int y0 = chunk << 3;   // 8 rows per block

  float acc[3][8], ks[3];
#pragma unroll
  for (int t = 0; t < 3; ++t) {
    ks[t] = 0.f;
#pragma unroll
    for (int e = 0; e < 8; ++e) acc[t][e] = 0.f;
  }

  float w[3], vf[8], wn[3], vn[8];
  loadrow3(kp, y0 + dy - 1, x, w);     // k row for iter 0
  loadv8(vp, y0, x, vf);               // v row for iter 0
  loadrow3(kp, y0 + dy, x, wn);        // prefetch iter 1
  loadv8(vp, y0 + 1, x, vn);           // y0+1 <= 249+1 < 256 always (chunk<32 -> y0<=248)

  for (int i = 0; i < 8; ++i) {
    int y = y0 + i;
#pragma unroll
    for (int t = 0; t < 3; ++t) {
      ks[t] += w[t];
#pragma unroll
      for (int e = 0; e < 8; ++e) acc[t][e] = fmaf(w[t], vf[e], acc[t][e]);
    }
#pragma unroll
    for (int t = 0; t < 3; ++t) w[t] = wn[t];
#pragma unroll
    for (int e = 0; e < 8; ++e) vf[e] = vn[e];
    loadrow3(kp, y + 1 + dy, x, wn);               // k row for iter i+2 (zeros past 255)
    int yv = y + 2;
    loadv8(vp, (yv < 256) ? yv : 255, x, vn);      // clamped prefetch (discarded at tail)
  }

  // Reduction: DPP sums within each 16-lane row, transpose 16 partials per
  // value through LDS, finish with 27 threads. Zero ds_swizzle traffic.
  __shared__ float red[16][27];
  int r16 = tid >> 4;
  bool wr = (tid & 15) == 0;
#pragma unroll
  for (int t = 0; t < 3; ++t) {
#pragma unroll
    for (int e = 0; e < 8; ++e) {
      float s = rowsum16(acc[t][e]);
      if (wr) red[r16][t * 8 + e] = s;
    }
    float s = rowsum16(ks[t]);
    if (wr) red[r16][24 + t] = s;
  }
  __syncthreads();
  if (tid < 27) {
    float s = 0.f;
#pragma unroll
    for (int j = 0; j < 16; ++j) s += red[j][tid];
    int dbase = (b * 8 + h) * 72 + c * 9 + dy * 3;  // taps p = 3*dy + t
    if (tid < 24) atomicAdd(&kv[((dbase + (tid >> 3)) << 3) + (tid & 7)], s);
    else atomicAdd(&ksum[dbase + (tid - 24)], s);
  }
}

// o -> PIXEL-MAJOR opx[n][64]: one 16B store per thread (channels h*8..h*8+7).
__global__ __launch_bounds__(256) void k_apply(bf16* __restrict__ qkv,
                                               bf16* __restrict__ opx,
                                               const float* __restrict__ kv,
                                               const float* __restrict__ ksum, int b) {
  int blk = blockIdx.x;
  int chunk = blk & 255, h = blk >> 8;
  int n = (chunk << 8) + threadIdx.x;
  int y = n >> 8, xx = n & 255;
  const float* kvb = kv + (size_t)((b * 8 + h) * 72) * 8;
  const float* ksb = ksum + (b * 8 + h) * 72;
  float num[8] = {0.f, 0.f, 0.f, 0.f, 0.f, 0.f, 0.f, 0.f};
  float den = 0.f;
  for (int c = 0; c < 8; ++c) {
    const bf16* qp = qkv + ((size_t)(h * 8 + c) << 16);
#pragma unroll
    for (int p = 0; p < 9; ++p) {
      int yy = y + p / 3 - 1, xc = xx + p % 3 - 1;
      float qv = 0.f;
      if ((unsigned)yy < 256u && (unsigned)xc < 256u) qv = b2f(qp[yy * 256 + xc]);
      int d = c * 9 + p;
      den = fmaf(qv, ksb[d], den);
#pragma unroll
      for (int e = 0; e < 8; ++e) num[e] = fmaf(qv, kvb[d * 8 + e], num[e]);
    }
  }
  float inv = 1.f / (den + 1e-6f);
  short8 ov;
#pragma unroll
  for (int e = 0; e < 8; ++e) ov[e] = f2bs(num[e] * inv);
  *(short8*)&opx[((size_t)n << 6) + h * 8] = ov;
}

// proj 3x3 conv via MFMA, LDS-free: B-fragments loaded directly from pixel-major opx.
// Grid dim3(2, 256); 256 thr; wave wv -> co [16wv,16wv+16).
__global__ __launch_bounds__(256) void k_proj_mfma(const bf16* __restrict__ opx,
                                                   const bf16* __restrict__ wpack,
                                                   const float* __restrict__ proj_b,
                                                   const float* __restrict__ x,
                                                   float* __restrict__ out, int b) {
  int tid = threadIdx.x;
  int wv = tid >> 6, ln = tid & 63;
  int half = blockIdx.x, y = blockIdx.y;
  int x0 = half << 7;
  int m = ln & 15, quad = ln >> 4;
  int co = wv * 16 + m;

  short8 afrag[18];
#pragma unroll
  for (int s = 0; s < 18; ++s) {
    int p = s >> 1;
    int ci0 = (s & 1) * 32 + quad * 8;
    afrag[s] = *(const short8*)&wpack[(p * 64 + co) * 64 + ci0];
  }

  floatx4 acc[8];
#pragma unroll
  for (int nt = 0; nt < 8; ++nt) acc[nt] = (floatx4){0.f, 0.f, 0.f, 0.f};

#pragma unroll
  for (int s = 0; s < 18; ++s) {
    int p = s >> 1;
    int dy = p / 3 - 1, dx = p % 3 - 1;
    int ci0 = (s & 1) * 32 + quad * 8;
    int gy = y + dy;
    bool yok = (unsigned)gy < 256u;
#pragma unroll
    for (int nt = 0; nt < 8; ++nt) {
      int gx = x0 + nt * 16 + m + dx;
      bool ok = yok && (unsigned)gx < 256u;
      int px = ok ? ((gy << 8) + gx) : 0;
      short8 bfrag = *(const short8*)&opx[((size_t)px << 6) + ci0];
      if (!ok) {
        short8 z = {0, 0, 0, 0, 0, 0, 0, 0};
        bfrag = z;
      }
      acc[nt] = __builtin_amdgcn_mfma_f32_16x16x32_bf16(afrag[s], bfrag, acc[nt], 0, 0, 0);
    }
  }

  float bias4[4];
#pragma unroll
  for (int r = 0; r < 4; ++r) bias4[r] = proj_b[wv * 16 + quad * 4 + r];
#pragma unroll
  for (int nt = 0; nt < 8; ++nt) {
    int gx = x0 + nt * 16 + m;
#pragma unroll
    for (int r = 0; r < 4; ++r) {
      int co_r = wv * 16 + quad * 4 + r;
      size_t idx = ((size_t)(b * 64 + co_r) << 16) + (y << 8) + gx;
      out[idx] = x[idx] + bias4[r] + acc[nt][r];
    }
  }
}

// depthwise 3x3 + GELU: h1 (q planes) -> h2 (k planes). Thread = element.
__global__ __launch_bounds__(256) void k_dw(bf16* __restrict__ qkv,
                                            const float* __restrict__ dw_w,
                                            const float* __restrict__ dw_b) {
  int gid = blockIdx.x * 256 + threadIdx.x;   // [0, 64*NPIX)
  int n = gid & 65535;
  int c = gid >> 16;
  int y = n >> 8, xx = n & 255;
  const bf16* ip = qkv + ((size_t)c << 16);
  float acc = dw_b[c];
#pragma unroll
  for (int p = 0; p < 9; ++p) {
    int yy = y + p / 3 - 1, xc = xx + p % 3 - 1;
    if ((unsigned)yy < 256u && (unsigned)xc < 256u)
      acc = fmaf(b2f(ip[yy * 256 + xc]), dw_w[c * 9 + p], acc);
  }
  qkv[((size_t)(64 + c) << 16) + n] = f2b(gelu_f(acc));
}

extern "C" void kernel_launch(void* const* d_in, const int* in_sizes, int n_in,
                              void* d_out, int out_size, void* d_ws, size_t ws_size,
                              hipStream_t stream) {
  const float* x      = (const float*)d_in[0];
  const float* qkv_w  = (const float*)d_in[1];
  const float* qkv_b  = (const float*)d_in[2];
  const float* proj_w = (const float*)d_in[3];
  const float* proj_b = (const float*)d_in[4];
  const float* ffn1_w = (const float*)d_in[5];
  const float* ffn1_b = (const float*)d_in[6];
  const float* dw_w   = (const float*)d_in[7];
  const float* dw_b   = (const float*)d_in[8];
  const float* ffn2_w = (const float*)d_in[9];
  const float* ffn2_b = (const float*)d_in[10];
  float* out = (float*)d_out;

  char* ws = (char*)d_ws;
  bf16*  qkvb  = (bf16*)(ws + OFF_QKV);
  bf16*  opx   = qkvb + ((size_t)128 << 16);   // v region, pixel-major [NPIX][64]
  float* kvb   = (float*)(ws + OFF_KV);
  float* ksb   = (float*)(ws + OFF_KS);
  bf16*  wpack = (bf16*)(ws + OFF_WP);

  k_zero<<<41, 256, 0, stream>>>(kvb, 10368);  // kv (9216) + ksum (1152), contiguous
  k_pack<<<144, 256, 0, stream>>>(proj_w, wpack);

  for (int b = 0; b < 2; ++b) {
    k_qkv_mfma<<<dim3(512, 3), 256, 0, stream>>>(x, qkv_w, qkv_b, qkvb, b);
    k_stats<<<dim3(96, 8, 8), 256, 0, stream>>>(qkvb, kvb, ksb, b);
    k_apply<<<2048, 256, 0, stream>>>(qkvb, opx, kvb, ksb, b);
    k_proj_mfma<<<dim3(2, 256), 256, 0, stream>>>(opx, wpack, proj_b, x, out, b);
    k_ffn1_mfma<<<512, 256, 0, stream>>>(out, ffn1_w, ffn1_b, qkvb, b);
    k_dw<<<16384, 256, 0, stream>>>(qkvb, dw_w, dw_b);
    k_ffn2_mfma<<<512, 256, 0, stream>>>(qkvb, ffn2_w, ffn2_b, out, b);
  }
}

// Round 3
// 365.956 us; speedup vs baseline: 2.3187x; 1.2764x over previous
//
#include <hip/hip_runtime.h>
#include <hip/hip_bf16.h>

typedef __hip_bfloat16 bf16;
typedef __attribute__((ext_vector_type(8))) short short8;
typedef __attribute__((ext_vector_type(4))) short short4v;
typedef __attribute__((ext_vector_type(4))) float floatx4;

#define NPIX 65536   // 256*256

__device__ __forceinline__ float b2f(bf16 v) { return __bfloat162float(v); }
__device__ __forceinline__ bf16 f2b(float v) { return __float2bfloat16(v); }
__device__ __forceinline__ short f2bs(float v) { bf16 t = __float2bfloat16(v); return *(short*)&t; }
__device__ __forceinline__ float us2f(unsigned short u) {
  union { unsigned int i; float f; } t; t.i = ((unsigned int)u) << 16; return t.f;
}
__device__ __forceinline__ float gelu_f(float v) {
  return 0.5f * v * (1.f + erff(v * 0.7071067811865476f));
}

// ---- workspace layout (bytes) ----
#define OFF_QKV 0u            // bf16 [192, NPIX]: q planes 0..63, k 64..127;
                              //   region 128..191 holds o as PIXEL-MAJOR [NPIX][64]
#define OFF_KV  25165824u     // fp32 [2,8,72,8]
#define OFF_KS  25202688u     // fp32 [2,8,72]
#define OFF_WP  25207296u     // bf16 wpack[9][64co][64ci] = 73,728 B

__global__ void k_zero(float* __restrict__ p, int n) {
  int i = blockIdx.x * 256 + threadIdx.x;
  if (i < n) p[i] = 0.f;
}

// pack proj_w [co][ci][p] fp32 -> wpack[p][co][ci] bf16 (A-fragment b128 source)
__global__ void k_pack(const float* __restrict__ pw, bf16* __restrict__ wpack) {
  int i = blockIdx.x * 256 + threadIdx.x;   // [0, 36864)
  int p = i >> 12, rem = i & 4095;
  int co = rem >> 6, ci = rem & 63;
  wpack[i] = f2b(pw[(co * 64 + ci) * 9 + p]);
}

// ============ shared MFMA-GEMM staging ============
__device__ __forceinline__ void stage_f32(const float* __restrict__ src, bf16* tile) {
  int tid = threadIdx.x;
  int px = tid & 127, chalf = tid >> 7;
#pragma unroll
  for (int it = 0; it < 8; ++it) {
    int ci0 = it * 8 + chalf * 4;
    short4v w;
#pragma unroll
    for (int j = 0; j < 4; ++j) w[j] = f2bs(src[((size_t)(ci0 + j) << 16) + px]);
    *(short4v*)&tile[px * 72 + ci0] = w;
  }
}

__device__ __forceinline__ void stage_bf16(const bf16* __restrict__ src, bf16* tile) {
  int tid = threadIdx.x;
  int px = tid & 127, chalf = tid >> 7;
  const unsigned short* s = (const unsigned short*)src;
#pragma unroll
  for (int it = 0; it < 8; ++it) {
    int ci0 = it * 8 + chalf * 4;
    short4v w;
#pragma unroll
    for (int j = 0; j < 4; ++j) w[j] = (short)s[((size_t)(ci0 + j) << 16) + px];
    *(short4v*)&tile[px * 72 + ci0] = w;
  }
}

// ============ qkv 1x1 conv via MFMA: grid (512 n-tiles, 3 sec) ============
__global__ __launch_bounds__(256) void k_qkv_mfma(const float* __restrict__ x,
                                                  const float* __restrict__ qkv_w,
                                                  const float* __restrict__ qkv_b,
                                                  bf16* __restrict__ qkv, int b) {
  __shared__ __align__(16) bf16 tile[128 * 72];
  int tid = threadIdx.x;
  int wv = tid >> 6, ln = tid & 63;
  int n0 = blockIdx.x << 7, sec = blockIdx.y;
  stage_f32(x + ((size_t)b << 22) + n0, tile);

  int m = ln & 15, quad = ln >> 4;
  int co = wv * 16 + m;
  const float* w = qkv_w + sec * 4096;
  short8 afrag[2];
#pragma unroll
  for (int s = 0; s < 2; ++s) {
    short8 af;
#pragma unroll
    for (int j = 0; j < 8; ++j) af[j] = f2bs(w[co * 64 + s * 32 + quad * 8 + j]);
    afrag[s] = af;
  }
  __syncthreads();

  floatx4 acc[8];
#pragma unroll
  for (int nt = 0; nt < 8; ++nt) acc[nt] = (floatx4){0.f, 0.f, 0.f, 0.f};
#pragma unroll
  for (int s = 0; s < 2; ++s) {
    int base = m * 72 + s * 32 + quad * 8;
#pragma unroll
    for (int nt = 0; nt < 8; ++nt) {
      short8 bfrag = *(const short8*)&tile[base + nt * 16 * 72];
      acc[nt] = __builtin_amdgcn_mfma_f32_16x16x32_bf16(afrag[s], bfrag, acc[nt], 0, 0, 0);
    }
  }

  bool relu = (sec < 2);
#pragma unroll
  for (int r = 0; r < 4; ++r) {
    int co_r = wv * 16 + quad * 4 + r;
    float bias = qkv_b[sec * 64 + co_r];
    bf16* op = qkv + ((size_t)(sec * 64 + co_r) << 16) + n0;
#pragma unroll
    for (int nt = 0; nt < 8; ++nt) {
      float v = acc[nt][r] + bias;
      if (relu) v = fmaxf(v, 0.f);
      op[nt * 16 + m] = f2b(v);
    }
  }
}

// ============ ffn1 1x1 conv + GELU via MFMA: grid 512 ============
__global__ __launch_bounds__(256) void k_ffn1_mfma(const float* __restrict__ xin,
                                                   const float* __restrict__ w1,
                                                   const float* __restrict__ b1,
                                                   bf16* __restrict__ qkv, int b) {
  __shared__ __align__(16) bf16 tile[128 * 72];
  int tid = threadIdx.x;
  int wv = tid >> 6, ln = tid & 63;
  int n0 = blockIdx.x << 7;
  stage_f32(xin + ((size_t)b << 22) + n0, tile);

  int m = ln & 15, quad = ln >> 4;
  int co = wv * 16 + m;
  short8 afrag[2];
#pragma unroll
  for (int s = 0; s < 2; ++s) {
    short8 af;
#pragma unroll
    for (int j = 0; j < 8; ++j) af[j] = f2bs(w1[co * 64 + s * 32 + quad * 8 + j]);
    afrag[s] = af;
  }
  __syncthreads();

  floatx4 acc[8];
#pragma unroll
  for (int nt = 0; nt < 8; ++nt) acc[nt] = (floatx4){0.f, 0.f, 0.f, 0.f};
#pragma unroll
  for (int s = 0; s < 2; ++s) {
    int base = m * 72 + s * 32 + quad * 8;
#pragma unroll
    for (int nt = 0; nt < 8; ++nt) {
      short8 bfrag = *(const short8*)&tile[base + nt * 16 * 72];
      acc[nt] = __builtin_amdgcn_mfma_f32_16x16x32_bf16(afrag[s], bfrag, acc[nt], 0, 0, 0);
    }
  }

#pragma unroll
  for (int r = 0; r < 4; ++r) {
    int co_r = wv * 16 + quad * 4 + r;
    float bias = b1[co_r];
    bf16* op = qkv + ((size_t)co_r << 16) + n0;
#pragma unroll
    for (int nt = 0; nt < 8; ++nt)
      op[nt * 16 + m] = f2b(gelu_f(acc[nt][r] + bias));
  }
}

// ============ ffn2 1x1 conv + residual via MFMA: grid 512 ============
__global__ __launch_bounds__(256) void k_ffn2_mfma(const bf16* __restrict__ qkv,
                                                   const float* __restrict__ w2,
                                                   const float* __restrict__ b2,
                                                   float* __restrict__ out, int b) {
  __shared__ __align__(16) bf16 tile[128 * 72];
  int tid = threadIdx.x;
  int wv = tid >> 6, ln = tid & 63;
  int n0 = blockIdx.x << 7;
  stage_bf16(qkv + ((size_t)64 << 16) + n0, tile);   // h2 in k planes

  int m = ln & 15, quad = ln >> 4;
  int co = wv * 16 + m;
  short8 afrag[2];
#pragma unroll
  for (int s = 0; s < 2; ++s) {
    short8 af;
#pragma unroll
    for (int j = 0; j < 8; ++j) af[j] = f2bs(w2[co * 64 + s * 32 + quad * 8 + j]);
    afrag[s] = af;
  }
  __syncthreads();

  floatx4 acc[8];
#pragma unroll
  for (int nt = 0; nt < 8; ++nt) acc[nt] = (floatx4){0.f, 0.f, 0.f, 0.f};
#pragma unroll
  for (int s = 0; s < 2; ++s) {
    int base = m * 72 + s * 32 + quad * 8;
#pragma unroll
    for (int nt = 0; nt < 8; ++nt) {
      short8 bfrag = *(const short8*)&tile[base + nt * 16 * 72];
      acc[nt] = __builtin_amdgcn_mfma_f32_16x16x32_bf16(afrag[s], bfrag, acc[nt], 0, 0, 0);
    }
  }

#pragma unroll
  for (int r = 0; r < 4; ++r) {
    int co_r = wv * 16 + quad * 4 + r;
    float bias = b2[co_r];
    float* op = out + ((size_t)b << 22) + ((size_t)co_r << 16) + n0;
#pragma unroll
    for (int nt = 0; nt < 8; ++nt) {
      int i = nt * 16 + m;
      op[i] = op[i] + bias + acc[nt][r];
    }
  }
}

// DPP butterfly add: v += dpp_permute(v). VALU-only, no DS-pipe traffic.
template <int CTRL>
__device__ __forceinline__ float dpp_add(float v) {
  int t = __builtin_amdgcn_update_dpp(0, __builtin_bit_cast(int, v), CTRL, 0xf, 0xf, true);
  return v + __builtin_bit_cast(float, t);
}

// sum across each row of 16 lanes (result in all 16 lanes of the row)
__device__ __forceinline__ float rowsum16(float v) {
  v = dpp_add<0xB1>(v);   // quad_perm(1,0,3,2)  : xor 1
  v = dpp_add<0x4E>(v);   // quad_perm(2,3,0,1)  : xor 2
  v = dpp_add<0x141>(v);  // row_half_mirror     : xor 4
  v = dpp_add<0x140>(v);  // row_mirror          : xor 8
  return v;
}

// load one bf16 image row segment [x0-1 .. x0+8] as floats (zeros at borders)
__device__ __forceinline__ void loadrow10(const unsigned short* __restrict__ plane,
                                          int y, int x0, float kf[10]) {
  if ((unsigned)y < 256u) {
    const unsigned short* row = plane + y * 256;
    short8 k8 = *(const short8*)&row[x0];
#pragma unroll
    for (int j = 0; j < 8; ++j) kf[1 + j] = us2f((unsigned short)k8[j]);
    kf[0] = (x0 > 0) ? us2f(row[x0 - 1]) : 0.f;
    kf[9] = (x0 + 8 < 256) ? us2f(row[x0 + 8]) : 0.f;
  } else {
#pragma unroll
    for (int j = 0; j < 10; ++j) kf[j] = 0.f;
  }
}

// Attention stats v7: 8 pixels/thread via short8 loads, one-shot (no loop).
// v4-v6 lesson: 11 scalar 2B VMEM per PIXEL was instruction-issue-bound
// (VALUBusy<=42%, HBM<6%). Now 17 VMEM per 8 pixels; 576 FMA/thread dense.
// Per-(p,e) partial fused straight into DPP rowsum16 so no 81-wide
// accumulator array stays live (~100 VGPR target).
__global__ __launch_bounds__(256) void k_stats(const bf16* __restrict__ qkv,
                                               float* __restrict__ kv,
                                               float* __restrict__ ksum, int b) {
  int tid = threadIdx.x;
  int chunk = blockIdx.x, c = blockIdx.y, h = blockIdx.z;
  int r = tid >> 5, xseg = tid & 31;
  int y = (chunk << 3) + r;
  int x0 = xseg << 3;
  const unsigned short* kp = (const unsigned short*)qkv + (((size_t)(64 + h * 8 + c)) << 16);
  const unsigned short* vp = (const unsigned short*)qkv + (((size_t)(128 + h * 8)) << 16);

  // 3 k rows, halo'd
  float kf[3][10];
#pragma unroll
  for (int rr = 0; rr < 3; ++rr) loadrow10(kp, y + rr - 1, x0, kf[rr]);

  // 8 v planes, 8 px each
  short8 varr[8];
#pragma unroll
  for (int e = 0; e < 8; ++e)
    varr[e] = *(const short8*)&vp[((size_t)e << 16) + y * 256 + x0];

  __shared__ float red[16][81];
  int r16 = tid >> 4;
  bool wr = (tid & 15) == 0;

  // ksum: 9 taps
#pragma unroll
  for (int rr = 0; rr < 3; ++rr)
#pragma unroll
    for (int t = 0; t < 3; ++t) {
      float s = 0.f;
#pragma unroll
      for (int i = 0; i < 8; ++i) s += kf[rr][i + t];
      s = rowsum16(s);
      if (wr) red[r16][72 + rr * 3 + t] = s;
    }

  // kv: 9 taps x 8 v-channels
#pragma unroll
  for (int e = 0; e < 8; ++e) {
    float vf[8];
#pragma unroll
    for (int i = 0; i < 8; ++i) vf[i] = us2f((unsigned short)varr[e][i]);
#pragma unroll
    for (int rr = 0; rr < 3; ++rr)
#pragma unroll
      for (int t = 0; t < 3; ++t) {
        float s = 0.f;
#pragma unroll
        for (int i = 0; i < 8; ++i) s = fmaf(kf[rr][i + t], vf[i], s);
        s = rowsum16(s);
        if (wr) red[r16][(rr * 3 + t) * 8 + e] = s;
      }
  }
  __syncthreads();
  if (tid < 81) {
    float s = 0.f;
#pragma unroll
    for (int j = 0; j < 16; ++j) s += red[j][tid];
    int dbase = (b * 8 + h) * 72 + c * 9;
    if (tid < 72) atomicAdd(&kv[((dbase + (tid >> 3)) << 3) + (tid & 7)], s);
    else atomicAdd(&ksum[dbase + (tid - 72)], s);
  }
}

// o -> PIXEL-MAJOR opx[n][64]: one 16B store per thread (channels h*8..h*8+7).
__global__ __launch_bounds__(256) void k_apply(bf16* __restrict__ qkv,
                                               bf16* __restrict__ opx,
                                               const float* __restrict__ kv,
                                               const float* __restrict__ ksum, int b) {
  int blk = blockIdx.x;
  int chunk = blk & 255, h = blk >> 8;
  int n = (chunk << 8) + threadIdx.x;
  int y = n >> 8, xx = n & 255;
  const float* kvb = kv + (size_t)((b * 8 + h) * 72) * 8;
  const float* ksb = ksum + (b * 8 + h) * 72;
  float num[8] = {0.f, 0.f, 0.f, 0.f, 0.f, 0.f, 0.f, 0.f};
  float den = 0.f;
  for (int c = 0; c < 8; ++c) {
    const bf16* qp = qkv + ((size_t)(h * 8 + c) << 16);
#pragma unroll
    for (int p = 0; p < 9; ++p) {
      int yy = y + p / 3 - 1, xc = xx + p % 3 - 1;
      float qv = 0.f;
      if ((unsigned)yy < 256u && (unsigned)xc < 256u) qv = b2f(qp[yy * 256 + xc]);
      int d = c * 9 + p;
      den = fmaf(qv, ksb[d], den);
#pragma unroll
      for (int e = 0; e < 8; ++e) num[e] = fmaf(qv, kvb[d * 8 + e], num[e]);
    }
  }
  float inv = 1.f / (den + 1e-6f);
  short8 ov;
#pragma unroll
  for (int e = 0; e < 8; ++e) ov[e] = f2bs(num[e] * inv);
  *(short8*)&opx[((size_t)n << 6) + h * 8] = ov;
}

// proj 3x3 conv via MFMA, LDS-free: B-fragments loaded directly from pixel-major opx.
// Grid dim3(2, 256); 256 thr; wave wv -> co [16wv,16wv+16).
__global__ __launch_bounds__(256) void k_proj_mfma(const bf16* __restrict__ opx,
                                                   const bf16* __restrict__ wpack,
                                                   const float* __restrict__ proj_b,
                                                   const float* __restrict__ x,
                                                   float* __restrict__ out, int b) {
  int tid = threadIdx.x;
  int wv = tid >> 6, ln = tid & 63;
  int half = blockIdx.x, y = blockIdx.y;
  int x0 = half << 7;
  int m = ln & 15, quad = ln >> 4;
  int co = wv * 16 + m;

  short8 afrag[18];
#pragma unroll
  for (int s = 0; s < 18; ++s) {
    int p = s >> 1;
    int ci0 = (s & 1) * 32 + quad * 8;
    afrag[s] = *(const short8*)&wpack[(p * 64 + co) * 64 + ci0];
  }

  floatx4 acc[8];
#pragma unroll
  for (int nt = 0; nt < 8; ++nt) acc[nt] = (floatx4){0.f, 0.f, 0.f, 0.f};

#pragma unroll
  for (int s = 0; s < 18; ++s) {
    int p = s >> 1;
    int dy = p / 3 - 1, dx = p % 3 - 1;
    int ci0 = (s & 1) * 32 + quad * 8;
    int gy = y + dy;
    bool yok = (unsigned)gy < 256u;
#pragma unroll
    for (int nt = 0; nt < 8; ++nt) {
      int gx = x0 + nt * 16 + m + dx;
      bool ok = yok && (unsigned)gx < 256u;
      int px = ok ? ((gy << 8) + gx) : 0;
      short8 bfrag = *(const short8*)&opx[((size_t)px << 6) + ci0];
      if (!ok) {
        short8 z = {0, 0, 0, 0, 0, 0, 0, 0};
        bfrag = z;
      }
      acc[nt] = __builtin_amdgcn_mfma_f32_16x16x32_bf16(afrag[s], bfrag, acc[nt], 0, 0, 0);
    }
  }

  float bias4[4];
#pragma unroll
  for (int r = 0; r < 4; ++r) bias4[r] = proj_b[wv * 16 + quad * 4 + r];
#pragma unroll
  for (int nt = 0; nt < 8; ++nt) {
    int gx = x0 + nt * 16 + m;
#pragma unroll
    for (int r = 0; r < 4; ++r) {
      int co_r = wv * 16 + quad * 4 + r;
      size_t idx = ((size_t)(b * 64 + co_r) << 16) + (y << 8) + gx;
      out[idx] = x[idx] + bias4[r] + acc[nt][r];
    }
  }
}

// depthwise 3x3 + GELU v2: 8 px/thread via short8 loads (same fix as k_stats).
// Block = one c plane slice: c = blk>>5 (weights wave-uniform -> scalar loads),
// 8 rows x 256 px per block. 9 VMEM + 72 FMA + 8 GELU per thread.
__global__ __launch_bounds__(256) void k_dw(bf16* __restrict__ qkv,
                                            const float* __restrict__ dw_w,
                                            const float* __restrict__ dw_b) {
  int blk = blockIdx.x;                 // [0, 2048): c*32 + rowchunk
  int c = blk >> 5;
  int y0 = (blk & 31) << 3;
  int tid = threadIdx.x;
  int r = tid >> 5, xseg = tid & 31;
  int y = y0 + r, x0 = xseg << 3;
  const unsigned short* ip = (const unsigned short*)qkv + ((size_t)c << 16);

  float w[9];
#pragma unroll
  for (int p = 0; p < 9; ++p) w[p] = dw_w[c * 9 + p];
  float bias = dw_b[c];

  float kf[3][10];
#pragma unroll
  for (int rr = 0; rr < 3; ++rr) loadrow10(ip, y + rr - 1, x0, kf[rr]);

  short8 ov;
#pragma unroll
  for (int i = 0; i < 8; ++i) {
    float acc = bias;
#pragma unroll
    for (int rr = 0; rr < 3; ++rr)
#pragma unroll
      for (int t = 0; t < 3; ++t)
        acc = fmaf(kf[rr][i + t], w[rr * 3 + t], acc);
    ov[i] = f2bs(gelu_f(acc));
  }
  *(short8*)&qkv[((size_t)(64 + c) << 16) + y * 256 + x0] = ov;
}

extern "C" void kernel_launch(void* const* d_in, const int* in_sizes, int n_in,
                              void* d_out, int out_size, void* d_ws, size_t ws_size,
                              hipStream_t stream) {
  const float* x      = (const float*)d_in[0];
  const float* qkv_w  = (const float*)d_in[1];
  const float* qkv_b  = (const float*)d_in[2];
  const float* proj_w = (const float*)d_in[3];
  const float* proj_b = (const float*)d_in[4];
  const float* ffn1_w = (const float*)d_in[5];
  const float* ffn1_b = (const float*)d_in[6];
  const float* dw_w   = (const float*)d_in[7];
  const float* dw_b   = (const float*)d_in[8];
  const float* ffn2_w = (const float*)d_in[9];
  const float* ffn2_b = (const float*)d_in[10];
  float* out = (float*)d_out;

  char* ws = (char*)d_ws;
  bf16*  qkvb  = (bf16*)(ws + OFF_QKV);
  bf16*  opx   = qkvb + ((size_t)128 << 16);   // v region, pixel-major [NPIX][64]
  float* kvb   = (float*)(ws + OFF_KV);
  float* ksb   = (float*)(ws + OFF_KS);
  bf16*  wpack = (bf16*)(ws + OFF_WP);

  k_zero<<<41, 256, 0, stream>>>(kvb, 10368);  // kv (9216) + ksum (1152), contiguous
  k_pack<<<144, 256, 0, stream>>>(proj_w, wpack);

  for (int b = 0; b < 2; ++b) {
    k_qkv_mfma<<<dim3(512, 3), 256, 0, stream>>>(x, qkv_w, qkv_b, qkvb, b);
    k_stats<<<dim3(32, 8, 8), 256, 0, stream>>>(qkvb, kvb, ksb, b);
    k_apply<<<2048, 256, 0, stream>>>(qkvb, opx, kvb, ksb, b);
    k_proj_mfma<<<dim3(2, 256), 256, 0, stream>>>(opx, wpack, proj_b, x, out, b);
    k_ffn1_mfma<<<512, 256, 0, stream>>>(out, ffn1_w, ffn1_b, qkvb, b);
    k_dw<<<2048, 256, 0, stream>>>(qkvb, dw_w, dw_b);
    k_ffn2_mfma<<<512, 256, 0, stream>>>(qkvb, ffn2_w, ffn2_b, out, b);
  }
}